// Round 12
// baseline (137.746 us; speedup 1.0000x reference)
//
#include <hip/hip_runtime.h>
#include <hip/hip_bf16.h>

typedef __attribute__((ext_vector_type(8)))  __bf16 bf16x8;
typedef __attribute__((ext_vector_type(16))) float  f32x16;
typedef __attribute__((ext_vector_type(4)))  float  f32x4;   // for nt stores

// Batched GEMM C[b] = A[b] @ B[b]^T, A/B:[8,4096,64] f32, C:[8,4096,4096] f32.
// Fabric-bytes model (confirmed R11: -40us from halving read bytes):
// writes + reads saturate ~6.9-7.2 TB/s regardless of locality/shape.
//   R5:  536+536 MB -> 155us | R11: 536+268+25 -> 115us (predicted 112-130)
// R12: 256x256 tile -> reads 268->134 MB. 1024-thread blocks, 16 waves (4x4),
// per-wave compute identical to R5 (64x64 via 2x2 32x32 MFMA). Epilogue: 4
// phases; wave-row p stages 64x256 slab in 64KB LDS, all waves NT-sweep
// (1KB full-row runs). bf16 pre-convert kept. Predicted 96-104us.

static __device__ inline bf16x8 to_bf16x8(const float4& a, const float4& b) {
    bf16x8 r;
    r[0] = (__bf16)a.x; r[1] = (__bf16)a.y; r[2] = (__bf16)a.z; r[3] = (__bf16)a.w;
    r[4] = (__bf16)b.x; r[5] = (__bf16)b.y; r[6] = (__bf16)b.z; r[7] = (__bf16)b.w;
    return r;
}

// ---- pass 1: fp32 -> bf16 conversion (8 floats/thread, one shot)
__global__ __launch_bounds__(256) void convert_bf16_kernel(
    const float* __restrict__ in, __bf16* __restrict__ out)
{
    const int i = blockIdx.x * 256 + threadIdx.x;
    const float4 v0 = ((const float4*)in)[2 * i];
    const float4 v1 = ((const float4*)in)[2 * i + 1];
    ((bf16x8*)out)[i] = to_bf16x8(v0, v1);
}

// ---- pass 2: GEMM 256x256 tile, bf16 inputs
__global__ __launch_bounds__(1024) void MatrixAttention_76149770158251_kernel(
    const __bf16* __restrict__ A16, const __bf16* __restrict__ B16,
    float* __restrict__ C)
{
    const int N = 4096, D = 64;
    __shared__ float tile[64 * 256];        // 64 KB: one epilogue slab

    const int tid  = threadIdx.x;
    const int lane = tid & 63;
    const int wid  = tid >> 6;              // 0..15
    const int wr   = wid >> 2;              // 4x4 wave grid
    const int wc   = wid & 3;
    const int bz   = blockIdx.z;

    const int brow = blockIdx.y * 256;
    const int bcol = blockIdx.x * 256;
    const int row0 = brow + wr * 64;
    const int col0 = bcol + wc * 64;

    const __bf16* __restrict__ Ab = A16 + (size_t)bz * N * D;
    const __bf16* __restrict__ Bb = B16 + (size_t)bz * N * D;
    float* __restrict__ Cb        = C   + (size_t)bz * N * N;

    const int lrow  = lane & 31;            // row within 32-frag
    const int khalf = (lane >> 5) * 8;      // 0 or 8: K slice

    f32x16 acc[2][2];
#pragma unroll
    for (int i = 0; i < 2; ++i)
#pragma unroll
        for (int j = 0; j < 2; ++j) acc[i][j] = (f32x16)0.0f;

    // A fragments for this wave's 64 rows (2 row-frags x 4 K-steps)
    bf16x8 af[2][4];
#pragma unroll
    for (int rb = 0; rb < 2; ++rb)
#pragma unroll
        for (int ks = 0; ks < 4; ++ks)
            af[rb][ks] = *(const bf16x8*)(
                Ab + (size_t)(row0 + rb * 32 + lrow) * D + ks * 16 + khalf);

#pragma unroll
    for (int cb = 0; cb < 2; ++cb)
#pragma unroll
        for (int ks = 0; ks < 4; ++ks) {
            bf16x8 bfr = *(const bf16x8*)(
                Bb + (size_t)(col0 + cb * 32 + lrow) * D + ks * 16 + khalf);
#pragma unroll
            for (int rb = 0; rb < 2; ++rb)
                acc[rb][cb] = __builtin_amdgcn_mfma_f32_32x32x16_bf16(
                    af[rb][ks], bfr, acc[rb][cb], 0, 0, 0);
        }

    // ---- 4-phase epilogue: wave-row p stages 64x256 slab; all waves sweep.
    // D layout (verified): C-col = lane&31, C-row = (v&3)+8*(v>>2)+4*(lane>>5)
    for (int p = 0; p < 4; ++p) {
        if (p) __syncthreads();             // previous sweep done (WAR)
        if (wr == p) {
#pragma unroll
            for (int rb = 0; rb < 2; ++rb)
#pragma unroll
                for (int cb = 0; cb < 2; ++cb) {
                    const int col   = wc * 64 + cb * 32 + (lane & 31);
                    const int rbase = rb * 32 + 4 * (lane >> 5);
#pragma unroll
                    for (int v = 0; v < 16; ++v) {
                        const int r = rbase + (v & 3) + 8 * (v >> 2);
                        tile[r * 256 + col] = acc[rb][cb][v];
                    }
                }
        }
        __syncthreads();

        // NT sweep: 4 iters x 1024 lanes x 16B; each row = 1KB contiguous run.
        const f32x4* t4 = (const f32x4*)tile;
        float* Cbase = Cb + (size_t)(brow + p * 64) * N + bcol;
#pragma unroll
        for (int it = 0; it < 4; ++it) {
            const int f = it * 1024 + tid;   // float4 index in slab
            const int r = f >> 6;            // 64 float4 per 256-col row
            const int c = f & 63;
            __builtin_nontemporal_store(t4[f], (f32x4*)(Cbase + (size_t)r * N + c * 4));
        }
    }
}

// ---- fallback: R5 verbatim (fp32 loads, 128x128) if ws too small
__global__ __launch_bounds__(256) void gemm_f32_kernel(
    const float* __restrict__ A, const float* __restrict__ Bm,
    float* __restrict__ C)
{
    const int N = 4096, D = 64;
    __shared__ float tile[128 * 128];
    const int lane = threadIdx.x & 63;
    const int wid  = threadIdx.x >> 6;
    const int wr   = wid >> 1;
    const int wc   = wid & 1;
    const int bz   = blockIdx.z;
    const int brow = blockIdx.y * 128;
    const int bcol = blockIdx.x * 128;
    const int row0 = brow + wr * 64;
    const int col0 = bcol + wc * 64;
    const float* __restrict__ Ab = A  + (size_t)bz * N * D;
    const float* __restrict__ Bb = Bm + (size_t)bz * N * D;
    float* __restrict__ Cb       = C  + (size_t)bz * N * N;
    const int lrow  = lane & 31;
    const int khalf = (lane >> 5) * 8;
    f32x16 acc[2][2];
#pragma unroll
    for (int i = 0; i < 2; ++i)
#pragma unroll
        for (int j = 0; j < 2; ++j) acc[i][j] = (f32x16)0.0f;
#pragma unroll
    for (int ks = 0; ks < 4; ++ks) {
        const int k = ks * 16 + khalf;
        bf16x8 af[2], bfr[2];
#pragma unroll
        for (int rb = 0; rb < 2; ++rb) {
            const float* p = Ab + (size_t)(row0 + rb * 32 + lrow) * D + k;
            af[rb] = to_bf16x8(*(const float4*)(p), *(const float4*)(p + 4));
        }
#pragma unroll
        for (int cb = 0; cb < 2; ++cb) {
            const float* p = Bb + (size_t)(col0 + cb * 32 + lrow) * D + k;
            bfr[cb] = to_bf16x8(*(const float4*)(p), *(const float4*)(p + 4));
        }
#pragma unroll
        for (int rb = 0; rb < 2; ++rb)
#pragma unroll
            for (int cb = 0; cb < 2; ++cb)
                acc[rb][cb] = __builtin_amdgcn_mfma_f32_32x32x16_bf16(
                    af[rb], bfr[cb], acc[rb][cb], 0, 0, 0);
    }
#pragma unroll
    for (int rb = 0; rb < 2; ++rb)
#pragma unroll
        for (int cb = 0; cb < 2; ++cb) {
            const int col   = wc * 64 + cb * 32 + (lane & 31);
            const int rbase = wr * 64 + rb * 32 + 4 * (lane >> 5);
#pragma unroll
            for (int v = 0; v < 16; ++v) {
                const int r = rbase + (v & 3) + 8 * (v >> 2);
                tile[r * 128 + col] = acc[rb][cb][v];
            }
        }
    __syncthreads();
    const f32x4* t4 = (const f32x4*)tile;
    float* Cbase = Cb + (size_t)brow * N + bcol;
#pragma unroll
    for (int it = 0; it < 16; ++it) {
        const int f  = it * 256 + threadIdx.x;
        const int r  = f >> 5;
        const int cq = f & 31;
        __builtin_nontemporal_store(t4[f], (f32x4*)(Cbase + (size_t)r * N + cq * 4));
    }
}

extern "C" void kernel_launch(void* const* d_in, const int* in_sizes, int n_in,
                              void* d_out, int out_size, void* d_ws, size_t ws_size,
                              hipStream_t stream) {
    const float* m1 = (const float*)d_in[0];
    const float* m2 = (const float*)d_in[1];
    float* out = (float*)d_out;

    const int N = 4096;
    const size_t elems = (size_t)8 * N * 64;           // 2,097,152 per tensor

    if (ws_size >= 2 * elems * sizeof(__bf16)) {
        __bf16* A16 = (__bf16*)d_ws;
        __bf16* B16 = A16 + elems;
        dim3 cgrid(elems / 8 / 256);                   // 1024 blocks
        convert_bf16_kernel<<<cgrid, dim3(256), 0, stream>>>(m1, A16);
        convert_bf16_kernel<<<cgrid, dim3(256), 0, stream>>>(m2, B16);
        dim3 grid(N / 256, N / 256, 8);
        MatrixAttention_76149770158251_kernel<<<grid, dim3(1024), 0, stream>>>(A16, B16, out);
    } else {
        dim3 grid(N / 128, N / 128, 8);
        gemm_f32_kernel<<<grid, dim3(256), 0, stream>>>(m1, m2, out);
    }
}

// Round 13
// 111.005 us; speedup vs baseline: 1.2409x; 1.2409x over previous
//
#include <hip/hip_runtime.h>
#include <hip/hip_bf16.h>

typedef __attribute__((ext_vector_type(8)))  __bf16 bf16x8;
typedef __attribute__((ext_vector_type(16))) float  f32x16;
typedef __attribute__((ext_vector_type(4)))  float  f32x4;   // for nt stores

// Batched GEMM C[b] = A[b] @ B[b]^T, A/B:[8,4096,64] f32, C:[8,4096,4096] f32.
// Fabric-bytes model (R11 confirmed: -40us from halving reads; R12 showed the
// 1024-thread block structure costs +40us -> keep R11's 256-thread structure).
// R13: each block = 128x512 strip as 4 sequential 128x128 quadrants. A frags
// loaded ONCE (registers), B per quadrant, R11's stage+NT-sweep per quadrant.
// Reads: 80KB per 256KB output -> 268->168 MB total. All else == R11.

static __device__ inline bf16x8 to_bf16x8(const float4& a, const float4& b) {
    bf16x8 r;
    r[0] = (__bf16)a.x; r[1] = (__bf16)a.y; r[2] = (__bf16)a.z; r[3] = (__bf16)a.w;
    r[4] = (__bf16)b.x; r[5] = (__bf16)b.y; r[6] = (__bf16)b.z; r[7] = (__bf16)b.w;
    return r;
}

// ---- pass 1: fp32 -> bf16 conversion (8 floats/thread, one shot)
__global__ __launch_bounds__(256) void convert_bf16_kernel(
    const float* __restrict__ in, __bf16* __restrict__ out)
{
    const int i = blockIdx.x * 256 + threadIdx.x;
    const float4 v0 = ((const float4*)in)[2 * i];
    const float4 v1 = ((const float4*)in)[2 * i + 1];
    ((bf16x8*)out)[i] = to_bf16x8(v0, v1);
}

// ---- pass 2: GEMM, 128x512 strip per block (4 quadrants, A reused)
__global__ __launch_bounds__(256) void MatrixAttention_76149770158251_kernel(
    const __bf16* __restrict__ A16, const __bf16* __restrict__ B16,
    float* __restrict__ C)
{
    const int N = 4096, D = 64;
    __shared__ float tile[128 * 128];       // 64 KB C-tile staging

    const int lane = threadIdx.x & 63;
    const int wid  = threadIdx.x >> 6;      // 0..3
    const int wr   = wid >> 1;              // 2x2 wave grid
    const int wc   = wid & 1;
    const int bz   = blockIdx.z;

    const int brow = blockIdx.y * 128;
    const int bcol = blockIdx.x * 512;      // strip base
    const int row0 = brow + wr * 64;

    const __bf16* __restrict__ Ab = A16 + (size_t)bz * N * D;
    const __bf16* __restrict__ Bb = B16 + (size_t)bz * N * D;
    float* __restrict__ Cb        = C   + (size_t)bz * N * N;

    const int lrow  = lane & 31;            // row within 32-frag
    const int khalf = (lane >> 5) * 8;      // 0 or 8: K slice

    // A fragments: loaded ONCE for the whole strip (2 row-frags x 4 K-steps)
    bf16x8 af[2][4];
#pragma unroll
    for (int rb = 0; rb < 2; ++rb)
#pragma unroll
        for (int ks = 0; ks < 4; ++ks)
            af[rb][ks] = *(const bf16x8*)(
                Ab + (size_t)(row0 + rb * 32 + lrow) * D + ks * 16 + khalf);

    for (int cq = 0; cq < 4; ++cq) {        // 4 column quadrants
        const int qcol = bcol + cq * 128;
        const int col0 = qcol + wc * 64;

        f32x16 acc[2][2];
#pragma unroll
        for (int i = 0; i < 2; ++i)
#pragma unroll
            for (int j = 0; j < 2; ++j) acc[i][j] = (f32x16)0.0f;

#pragma unroll
        for (int ks = 0; ks < 4; ++ks) {
            bf16x8 bfr[2];
#pragma unroll
            for (int cb = 0; cb < 2; ++cb)
                bfr[cb] = *(const bf16x8*)(
                    Bb + (size_t)(col0 + cb * 32 + lrow) * D + ks * 16 + khalf);
#pragma unroll
            for (int rb = 0; rb < 2; ++rb)
#pragma unroll
                for (int cb = 0; cb < 2; ++cb)
                    acc[rb][cb] = __builtin_amdgcn_mfma_f32_32x32x16_bf16(
                        af[rb][ks], bfr[cb], acc[rb][cb], 0, 0, 0);
        }

        if (cq) __syncthreads();            // WAR: previous sweep done

        // stage acc -> LDS (verified D layout: col=lane&31,
        // row=(v&3)+8*(v>>2)+4*(lane>>5))
#pragma unroll
        for (int rb = 0; rb < 2; ++rb)
#pragma unroll
            for (int cb = 0; cb < 2; ++cb) {
                const int col   = wc * 64 + cb * 32 + (lane & 31);
                const int rbase = wr * 64 + rb * 32 + 4 * (lane >> 5);
#pragma unroll
                for (int v = 0; v < 16; ++v) {
                    const int r = rbase + (v & 3) + 8 * (v >> 2);
                    tile[r * 128 + col] = acc[rb][cb][v];
                }
            }

        __syncthreads();

        // NT store sweep — identical to R11 (512B runs, dwordx4, nt).
        const f32x4* t4 = (const f32x4*)tile;
        float* Cbase = Cb + (size_t)brow * N + qcol;
#pragma unroll
        for (int it = 0; it < 16; ++it) {
            const int f  = it * 256 + threadIdx.x;
            const int r  = f >> 5;
            const int cq4 = f & 31;
            __builtin_nontemporal_store(t4[f], (f32x4*)(Cbase + (size_t)r * N + cq4 * 4));
        }
    }
}

// ---- fallback: R5 verbatim (fp32 loads, 128x128) if ws too small
__global__ __launch_bounds__(256) void gemm_f32_kernel(
    const float* __restrict__ A, const float* __restrict__ Bm,
    float* __restrict__ C)
{
    const int N = 4096, D = 64;
    __shared__ float tile[128 * 128];
    const int lane = threadIdx.x & 63;
    const int wid  = threadIdx.x >> 6;
    const int wr   = wid >> 1;
    const int wc   = wid & 1;
    const int bz   = blockIdx.z;
    const int brow = blockIdx.y * 128;
    const int bcol = blockIdx.x * 128;
    const int row0 = brow + wr * 64;
    const int col0 = bcol + wc * 64;
    const float* __restrict__ Ab = A  + (size_t)bz * N * D;
    const float* __restrict__ Bb = Bm + (size_t)bz * N * D;
    float* __restrict__ Cb       = C  + (size_t)bz * N * N;
    const int lrow  = lane & 31;
    const int khalf = (lane >> 5) * 8;
    f32x16 acc[2][2];
#pragma unroll
    for (int i = 0; i < 2; ++i)
#pragma unroll
        for (int j = 0; j < 2; ++j) acc[i][j] = (f32x16)0.0f;
#pragma unroll
    for (int ks = 0; ks < 4; ++ks) {
        const int k = ks * 16 + khalf;
        bf16x8 af[2], bfr[2];
#pragma unroll
        for (int rb = 0; rb < 2; ++rb) {
            const float* p = Ab + (size_t)(row0 + rb * 32 + lrow) * D + k;
            af[rb] = to_bf16x8(*(const float4*)(p), *(const float4*)(p + 4));
        }
#pragma unroll
        for (int cb = 0; cb < 2; ++cb) {
            const float* p = Bb + (size_t)(col0 + cb * 32 + lrow) * D + k;
            bfr[cb] = to_bf16x8(*(const float4*)(p), *(const float4*)(p + 4));
        }
#pragma unroll
        for (int rb = 0; rb < 2; ++rb)
#pragma unroll
            for (int cb = 0; cb < 2; ++cb)
                acc[rb][cb] = __builtin_amdgcn_mfma_f32_32x32x16_bf16(
                    af[rb], bfr[cb], acc[rb][cb], 0, 0, 0);
    }
#pragma unroll
    for (int rb = 0; rb < 2; ++rb)
#pragma unroll
        for (int cb = 0; cb < 2; ++cb) {
            const int col   = wc * 64 + cb * 32 + (lane & 31);
            const int rbase = wr * 64 + rb * 32 + 4 * (lane >> 5);
#pragma unroll
            for (int v = 0; v < 16; ++v) {
                const int r = rbase + (v & 3) + 8 * (v >> 2);
                tile[r * 128 + col] = acc[rb][cb][v];
            }
        }
    __syncthreads();
    const f32x4* t4 = (const f32x4*)tile;
    float* Cbase = Cb + (size_t)brow * N + bcol;
#pragma unroll
    for (int it = 0; it < 16; ++it) {
        const int f  = it * 256 + threadIdx.x;
        const int r  = f >> 5;
        const int cq = f & 31;
        __builtin_nontemporal_store(t4[f], (f32x4*)(Cbase + (size_t)r * N + cq * 4));
    }
}

extern "C" void kernel_launch(void* const* d_in, const int* in_sizes, int n_in,
                              void* d_out, int out_size, void* d_ws, size_t ws_size,
                              hipStream_t stream) {
    const float* m1 = (const float*)d_in[0];
    const float* m2 = (const float*)d_in[1];
    float* out = (float*)d_out;

    const int N = 4096;
    const size_t elems = (size_t)8 * N * 64;           // 2,097,152 per tensor

    if (ws_size >= 2 * elems * sizeof(__bf16)) {
        __bf16* A16 = (__bf16*)d_ws;
        __bf16* B16 = A16 + elems;
        dim3 cgrid(elems / 8 / 256);                   // 1024 blocks
        convert_bf16_kernel<<<cgrid, dim3(256), 0, stream>>>(m1, A16);
        convert_bf16_kernel<<<cgrid, dim3(256), 0, stream>>>(m2, B16);
        dim3 grid(N / 512, N / 128, 8);                // 8 x 32 x 8 = 2048
        MatrixAttention_76149770158251_kernel<<<grid, dim3(256), 0, stream>>>(A16, B16, out);
    } else {
        dim3 grid(N / 128, N / 128, 8);
        gemm_f32_kernel<<<grid, dim3(256), 0, stream>>>(m1, m2, out);
    }
}